// Round 4
// baseline (2184.402 us; speedup 1.0000x reference)
//
#include <hip/hip_runtime.h>
#include <math.h>

// RoPE attention forward, fp32 baseline (round 3 — added ws_size guard;
// compute byte-identical to rounds 1-2; kernel has never executed on HW).
// B=4, T=2048, D_MODEL=1024, H=16, D=64.
// Pipeline: rope_table -> Q/K/V projections (RoPE fused in epilogue, head
// layout [B][H][T][D]) -> flash attention (64x64 tiles, online softmax)
// -> output projection + bias.
// ws layout (floats): q(8.4M) k(8.4M) v(8.4M) ctx(8.4M) sin(64K) cos(64K)
// = 134,742,016 bytes (~128.5 MiB). If ws_size is smaller we launch nothing
// (clean "incorrect" instead of an OOB-write container crash).

#define TSEQ 2048
#define DMODEL 1024
#define NHEAD 16
#define HDIM 64
#define BATCH 4

#define BM 128
#define BN 128
#define BK 16
#define LDA 132   // BM+4: keeps float4 row alignment, 2-way-max bank aliasing
#define LDB 132

#define QT 64
#define KT 64
#define LQK 66    // pad for float2 k-reads, 4-way max conflicts
#define LVP 68    // pad for float4 dim-reads (16B-aligned rows)

__global__ __launch_bounds__(256)
void rope_table_kernel(float* __restrict__ sint, float* __restrict__ cost)
{
    int idx = blockIdx.x * 256 + threadIdx.x;   // [0, TSEQ*32)
    if (idx >= TSEQ * 32) return;
    int t = idx >> 5;
    int i = idx & 31;
    // Match reference: inv_freq rounded to fp32, angle = fp32(t * inv_freq),
    // then exact sin/cos of that fp32 angle.
    float inv32 = (float)pow(10000.0, -(double)i / 32.0);
    float ang = (float)t * inv32;
    sint[idx] = (float)sin((double)ang);
    cost[idx] = (float)cos((double)ang);
}

// MODE 0: head layout, no rope (V)
// MODE 1: head layout + rope, * post_scale (Q: 0.125, K: 1.0)
// MODE 2: flat [M][N] + bias (output projection)
template<int MODE>
__global__ __launch_bounds__(256)
void proj_gemm(const float* __restrict__ A, const float* __restrict__ W,
               const float* __restrict__ bias, float* __restrict__ out,
               const float* __restrict__ sint, const float* __restrict__ cost,
               float post_scale)
{
    __shared__ float As[BK][LDA];
    __shared__ float Bs[BK][LDB];

    const int tid = threadIdx.x;
    const int tx = tid & 15;
    const int ty = tid >> 4;
    const int bx = blockIdx.x;   // N tile
    const int by = blockIdx.y;   // M tile

    // Column mapping: thread owns {coA..coA+3} and {coB..coB+3} = RoPE pairs
    // (d, d+32) within one head. q2 = head within the 128-col tile.
    const int q2  = tx >> 3;
    const int r0  = (tx & 7) << 2;   // 0..28, d = r0+j < 32
    const int coA = q2 * 64 + r0;
    const int coB = coA + 32;
    const int row0 = ty << 3;

    // staging: 512 float4 per matrix per k-tile, 2 per thread
    const int lr = tid >> 2;          // 0..63
    const int lc = (tid & 3) << 2;    // 0,4,8,12

    const float* Ap = A + (size_t)(by * BM) * DMODEL;
    const float* Wp = W + (size_t)(bx * BN) * DMODEL;

    float acc[8][8];
    #pragma unroll
    for (int i = 0; i < 8; i++)
        #pragma unroll
        for (int j = 0; j < 8; j++) acc[i][j] = 0.f;

    for (int k0 = 0; k0 < DMODEL; k0 += BK) {
        float4 a0 = *(const float4*)(Ap + (size_t)lr * DMODEL + k0 + lc);
        float4 a1 = *(const float4*)(Ap + (size_t)(lr + 64) * DMODEL + k0 + lc);
        float4 b0 = *(const float4*)(Wp + (size_t)lr * DMODEL + k0 + lc);
        float4 b1 = *(const float4*)(Wp + (size_t)(lr + 64) * DMODEL + k0 + lc);
        __syncthreads();
        #pragma unroll
        for (int c = 0; c < 4; c++) {
            As[lc + c][lr]      = (&a0.x)[c];
            As[lc + c][lr + 64] = (&a1.x)[c];
            Bs[lc + c][lr]      = (&b0.x)[c];
            Bs[lc + c][lr + 64] = (&b1.x)[c];
        }
        __syncthreads();
        #pragma unroll
        for (int kk = 0; kk < BK; kk++) {
            const float4 av0 = *(const float4*)&As[kk][row0];
            const float4 av1 = *(const float4*)&As[kk][row0 + 4];
            const float4 bv0 = *(const float4*)&Bs[kk][coA];
            const float4 bv1 = *(const float4*)&Bs[kk][coB];
            const float a[8] = {av0.x, av0.y, av0.z, av0.w, av1.x, av1.y, av1.z, av1.w};
            const float b[8] = {bv0.x, bv0.y, bv0.z, bv0.w, bv1.x, bv1.y, bv1.z, bv1.w};
            #pragma unroll
            for (int i = 0; i < 8; i++)
                #pragma unroll
                for (int j = 0; j < 8; j++)
                    acc[i][j] = fmaf(a[i], b[j], acc[i][j]);
        }
    }

    if (MODE == 2) {
        const float4 ba = *(const float4*)(bias + bx * BN + coA);
        const float4 bb = *(const float4*)(bias + bx * BN + coB);
        #pragma unroll
        for (int i = 0; i < 8; i++) {
            int m = by * BM + row0 + i;
            float4 oa, ob;
            oa.x = acc[i][0] + ba.x; oa.y = acc[i][1] + ba.y;
            oa.z = acc[i][2] + ba.z; oa.w = acc[i][3] + ba.w;
            ob.x = acc[i][4] + bb.x; ob.y = acc[i][5] + bb.y;
            ob.z = acc[i][6] + bb.z; ob.w = acc[i][7] + bb.w;
            float* op = out + (size_t)m * DMODEL + bx * BN;
            *(float4*)(op + coA) = oa;
            *(float4*)(op + coB) = ob;
        }
    } else {
        const int h = bx * 2 + q2;
        #pragma unroll
        for (int i = 0; i < 8; i++) {
            int m = by * BM + row0 + i;
            int bb2 = m >> 11;       // / TSEQ
            int t   = m & 2047;
            float4 oa, ob;
            if (MODE == 1) {
                const float4 sn = *(const float4*)(sint + t * 32 + r0);
                const float4 cn = *(const float4*)(cost + t * 32 + r0);
                oa.x = (acc[i][0] * cn.x - acc[i][4] * sn.x) * post_scale;
                oa.y = (acc[i][1] * cn.y - acc[i][5] * sn.y) * post_scale;
                oa.z = (acc[i][2] * cn.z - acc[i][6] * sn.z) * post_scale;
                oa.w = (acc[i][3] * cn.w - acc[i][7] * sn.w) * post_scale;
                ob.x = (acc[i][4] * cn.x + acc[i][0] * sn.x) * post_scale;
                ob.y = (acc[i][5] * cn.y + acc[i][1] * sn.y) * post_scale;
                ob.z = (acc[i][6] * cn.z + acc[i][2] * sn.z) * post_scale;
                ob.w = (acc[i][7] * cn.w + acc[i][3] * sn.w) * post_scale;
            } else {
                oa.x = acc[i][0]; oa.y = acc[i][1]; oa.z = acc[i][2]; oa.w = acc[i][3];
                ob.x = acc[i][4]; ob.y = acc[i][5]; ob.z = acc[i][6]; ob.w = acc[i][7];
            }
            float* op = out + ((size_t)(bb2 * NHEAD + h) * TSEQ + t) * HDIM;
            *(float4*)(op + r0)      = oa;
            *(float4*)(op + r0 + 32) = ob;
        }
    }
}

__global__ __launch_bounds__(256)
void flash_attn(const float* __restrict__ Q, const float* __restrict__ K,
                const float* __restrict__ V, float* __restrict__ ctx)
{
    __shared__ float Qs[QT][LQK];
    __shared__ float Ks[KT][LQK];
    __shared__ float Vs[KT][LVP];
    __shared__ float Ps[QT][LVP];

    const int tid = threadIdx.x;
    const int tx = tid & 15;
    const int ty = tid >> 4;
    const int qt = blockIdx.x;   // q tile
    const int bh = blockIdx.y;   // b*16 + h

    const float* Qp = Q + ((size_t)bh * TSEQ + qt * QT) * HDIM;
    const float* Kp = K + (size_t)bh * TSEQ * HDIM;
    const float* Vp = V + (size_t)bh * TSEQ * HDIM;

    // load Q tile (already scaled by 1/sqrt(d) and RoPE'd in projection)
    #pragma unroll
    for (int r = 0; r < 4; r++) {
        int id = tid + 256 * r;
        int row = id >> 4;
        int c = (id & 15) << 2;
        float4 t4 = *(const float4*)(Qp + (size_t)row * HDIM + c);
        Qs[row][c + 0] = t4.x; Qs[row][c + 1] = t4.y;
        Qs[row][c + 2] = t4.z; Qs[row][c + 3] = t4.w;
    }

    float m_i[4], l_i[4];
    float4 o4[4];
    #pragma unroll
    for (int i = 0; i < 4; i++) {
        m_i[i] = -1e30f;
        l_i[i] = 0.f;
        o4[i].x = 0.f; o4[i].y = 0.f; o4[i].z = 0.f; o4[i].w = 0.f;
    }

    for (int kt = 0; kt < TSEQ / KT; ++kt) {
        // prefetch K/V tile into regs before barrier (hides latency under it)
        float4 kr[4], vr[4];
        int rows[4], cs[4];
        #pragma unroll
        for (int r = 0; r < 4; r++) {
            int id = tid + 256 * r;
            rows[r] = id >> 4;
            cs[r] = (id & 15) << 2;
            kr[r] = *(const float4*)(Kp + (size_t)(kt * KT + rows[r]) * HDIM + cs[r]);
            vr[r] = *(const float4*)(Vp + (size_t)(kt * KT + rows[r]) * HDIM + cs[r]);
        }
        __syncthreads();   // prior PV done (and Q publish on iter 0)
        #pragma unroll
        for (int r = 0; r < 4; r++) {
            #pragma unroll
            for (int c = 0; c < 4; c++) {
                Ks[rows[r]][cs[r] + c] = (&kr[r].x)[c];
                Vs[rows[r]][cs[r] + c] = (&vr[r].x)[c];
            }
        }
        __syncthreads();

        // S = Q K^T, 4x4 per thread
        float s[4][4];
        #pragma unroll
        for (int i = 0; i < 4; i++)
            #pragma unroll
            for (int j = 0; j < 4; j++) s[i][j] = 0.f;

        #pragma unroll 8
        for (int k2 = 0; k2 < HDIM / 2; k2++) {
            float2 qa[4], kb[4];
            #pragma unroll
            for (int i = 0; i < 4; i++) qa[i] = *(const float2*)&Qs[ty * 4 + i][k2 * 2];
            #pragma unroll
            for (int j = 0; j < 4; j++) kb[j] = *(const float2*)&Ks[tx * 4 + j][k2 * 2];
            #pragma unroll
            for (int i = 0; i < 4; i++)
                #pragma unroll
                for (int j = 0; j < 4; j++) {
                    s[i][j] = fmaf(qa[i].x, kb[j].x, s[i][j]);
                    s[i][j] = fmaf(qa[i].y, kb[j].y, s[i][j]);
                }
        }

        // online softmax; row r = ty*4+i lives on the 16 lanes sharing ty
        float corr[4];
        #pragma unroll
        for (int i = 0; i < 4; i++) {
            float r = fmaxf(fmaxf(s[i][0], s[i][1]), fmaxf(s[i][2], s[i][3]));
            r = fmaxf(r, __shfl_xor(r, 1));
            r = fmaxf(r, __shfl_xor(r, 2));
            r = fmaxf(r, __shfl_xor(r, 4));
            r = fmaxf(r, __shfl_xor(r, 8));
            float mn = fmaxf(m_i[i], r);
            corr[i] = __expf(m_i[i] - mn);
            m_i[i] = mn;
        }
        #pragma unroll
        for (int i = 0; i < 4; i++) {
            float sum = 0.f;
            #pragma unroll
            for (int j = 0; j < 4; j++) {
                float p = __expf(s[i][j] - m_i[i]);
                s[i][j] = p;
                sum += p;
            }
            sum += __shfl_xor(sum, 1);
            sum += __shfl_xor(sum, 2);
            sum += __shfl_xor(sum, 4);
            sum += __shfl_xor(sum, 8);
            l_i[i] = l_i[i] * corr[i] + sum;
        }
        #pragma unroll
        for (int i = 0; i < 4; i++) {
            o4[i].x *= corr[i]; o4[i].y *= corr[i];
            o4[i].z *= corr[i]; o4[i].w *= corr[i];
            #pragma unroll
            for (int j = 0; j < 4; j++) Ps[ty * 4 + i][tx * 4 + j] = s[i][j];
        }
        __syncthreads();

        // O += P V
        #pragma unroll 8
        for (int kv = 0; kv < KT; kv++) {
            float4 vv = *(const float4*)&Vs[kv][tx << 2];
            float pi[4];
            #pragma unroll
            for (int i = 0; i < 4; i++) pi[i] = Ps[ty * 4 + i][kv];
            #pragma unroll
            for (int i = 0; i < 4; i++) {
                o4[i].x = fmaf(pi[i], vv.x, o4[i].x);
                o4[i].y = fmaf(pi[i], vv.y, o4[i].y);
                o4[i].z = fmaf(pi[i], vv.z, o4[i].z);
                o4[i].w = fmaf(pi[i], vv.w, o4[i].w);
            }
        }
    }

    const int b = bh >> 4, h = bh & 15;
    #pragma unroll
    for (int i = 0; i < 4; i++) {
        float inv = 1.0f / l_i[i];
        float4 o = o4[i];
        o.x *= inv; o.y *= inv; o.z *= inv; o.w *= inv;
        size_t t = qt * QT + ty * 4 + i;
        *(float4*)(ctx + ((size_t)b * TSEQ + t) * DMODEL + h * HDIM + (tx << 2)) = o;
    }
}

extern "C" void kernel_launch(void* const* d_in, const int* in_sizes, int n_in,
                              void* d_out, int out_size, void* d_ws, size_t ws_size,
                              hipStream_t stream)
{
    const float* x  = (const float*)d_in[0];
    const float* Wq = (const float*)d_in[1];
    const float* Wk = (const float*)d_in[2];
    const float* Wv = (const float*)d_in[3];
    const float* Wo = (const float*)d_in[4];
    const float* bo = (const float*)d_in[5];
    float* out = (float*)d_out;

    float* ws = (float*)d_ws;
    const size_t NELT = (size_t)BATCH * TSEQ * DMODEL;  // 8388608
    const size_t WS_REQ = (4 * NELT + 2 * (size_t)TSEQ * 32) * sizeof(float);
    if (ws_size < WS_REQ) {
        // Insufficient scratch: launching would write OOB (possible container
        // crash). Do nothing -> clean validation failure as the diagnostic.
        return;
    }
    float* q    = ws;
    float* k    = q + NELT;
    float* v    = k + NELT;
    float* ctx  = v + NELT;
    float* sint = ctx + NELT;
    float* cost = sint + (size_t)TSEQ * 32;

    rope_table_kernel<<<256, 256, 0, stream>>>(sint, cost);

    dim3 pg(DMODEL / BN, (BATCH * TSEQ) / BM);
    // Q gets the 1/sqrt(64) softmax scale folded in (commutes with rotation).
    proj_gemm<1><<<pg, 256, 0, stream>>>(x, Wq, nullptr, q, sint, cost, 0.125f);
    proj_gemm<1><<<pg, 256, 0, stream>>>(x, Wk, nullptr, k, sint, cost, 1.0f);
    proj_gemm<0><<<pg, 256, 0, stream>>>(x, Wv, nullptr, v, sint, cost, 1.0f);

    flash_attn<<<dim3(TSEQ / QT, BATCH * NHEAD), 256, 0, stream>>>(q, k, v, ctx);

    proj_gemm<2><<<pg, 256, 0, stream>>>(ctx, Wo, bo, out, nullptr, nullptr, 1.0f);
}

// Round 11
// 568.771 us; speedup vs baseline: 3.8406x; 3.8406x over previous
//
#include <hip/hip_runtime.h>
#include <math.h>

// RoPE attention forward — fp16 MFMA pipeline (round 10 resubmit; unchanged —
// infra failures, kernel has never executed on HW).
// B=4, T=2048, D_MODEL=1024, H=16, D=64.
// rope_table(fp32) -> mm16<1> Q (RoPE+0.125), mm16<1> K (RoPE), mm16<0> V
//   (each: x fp32 -> fp16 LDS staging -> 16x16x32 f16 MFMA -> fp16 head
//    layout [B*H][T][D]) -> flash16 (64x64 tiles, MFMA QK^T and PV, fp32
//    online softmax) -> mm16<2> out = ctx*Wo^T + bo (fp32 out).
// MFMA layout (HW-verified m89): C/D row=(lane>>4)*4+reg, col=lane&15;
// A/B frags: lane reads 8 consecutive k at k-offset (lane>>4)*8 from
// row (lane&15) — k-permutation cancels between A and B.
// Range audit: all fp16-stored tensors O(1) (q,k,v,S,P,O,ctx) — no overflow.
// ws (f16): qh,kh,vh,ctxh 4x16.78MB + sin/cos fp32 tables = ~67.6 MB.

typedef _Float16 f16;
typedef _Float16 f16x8 __attribute__((ext_vector_type(8)));
typedef _Float16 f16x4 __attribute__((ext_vector_type(4)));
typedef float f32x4 __attribute__((ext_vector_type(4)));

#define TSEQ 2048
#define DMODEL 1024
#define NHEAD 16
#define HDIM 64
#define BATCH 4

#define MFMA16(a, b, c) __builtin_amdgcn_mfma_f32_16x16x32_f16((a), (b), (c), 0, 0, 0)

__global__ __launch_bounds__(256)
void rope_table_kernel(float* __restrict__ sint, float* __restrict__ cost)
{
    int idx = blockIdx.x * 256 + threadIdx.x;   // [0, TSEQ*32)
    if (idx >= TSEQ * 32) return;
    int t = idx >> 5;
    int i = idx & 31;
    float inv32 = (float)pow(10000.0, -(double)i / 32.0);
    float ang = (float)t * inv32;
    sint[idx] = (float)sin((double)ang);
    cost[idx] = (float)cos((double)ang);
}

// MODE 0: A=x fp32, out fp16 head layout (V)
// MODE 1: A=x fp32, out fp16 head layout + RoPE * post_scale (Q,K)
// MODE 2: A=ctx fp16, out fp32 flat + bias (final projection)
// Tile 128x128, BK=32, 4 waves (2 M x 2 N), per-wave 64x64 = 4x4 MFMA frags.
template<int MODE>
__global__ __launch_bounds__(256)
void mm16(const void* __restrict__ Ap_, const float* __restrict__ W,
          const float* __restrict__ bias, void* __restrict__ outp,
          const float* __restrict__ sint, const float* __restrict__ cost,
          float post_scale)
{
    __shared__ __align__(16) f16 As[128][40];   // 40 = 32 + 8 pad; 80B rows
    __shared__ __align__(16) f16 Bs[128][40];

    const int tid = threadIdx.x;
    const int bx = blockIdx.x;    // N tile (0..7)
    const int by = blockIdx.y;    // M tile (0..63)
    const int w = tid >> 6;
    const int lane = tid & 63;
    const int lr = lane & 15;
    const int lg = lane >> 4;     // 0..3
    const int wm = (w >> 1) * 64;
    const int wn = (w & 1) * 64;
    const int m0 = by * 128, n0 = bx * 128;

    f32x4 acc[4][4];
    #pragma unroll
    for (int i = 0; i < 4; i++)
        #pragma unroll
        for (int j = 0; j < 4; j++) acc[i][j] = (f32x4)0.0f;

    // staging index maps
    const int srow = tid >> 3;            // fp32 path: 0..31 (+32p)
    const int skc  = (tid & 7) * 4;       // fp32: 4-float chunks
    const int hrow = tid >> 2;            // fp16 path rows 0..63 (+64p)
    const int hkc  = (tid & 3) * 8;       // fp16: 8-half chunks

    for (int k0 = 0; k0 < DMODEL; k0 += 32) {
        float4 ww[4];
        float4 aw[4];
        f16x8 ah[2];
        if (MODE < 2) {
            const float* A = (const float*)Ap_;
            #pragma unroll
            for (int p = 0; p < 4; p++)
                aw[p] = *(const float4*)(A + (size_t)(m0 + srow + 32 * p) * DMODEL + k0 + skc);
        } else {
            const f16* A = (const f16*)Ap_;
            #pragma unroll
            for (int p = 0; p < 2; p++)
                ah[p] = *(const f16x8*)(A + (size_t)(m0 + hrow + 64 * p) * DMODEL + k0 + hkc);
        }
        #pragma unroll
        for (int p = 0; p < 4; p++)
            ww[p] = *(const float4*)(W + (size_t)(n0 + srow + 32 * p) * DMODEL + k0 + skc);

        __syncthreads();   // previous iteration's frag reads done

        if (MODE < 2) {
            #pragma unroll
            for (int p = 0; p < 4; p++) {
                f16x4 hv;
                hv[0] = (f16)aw[p].x; hv[1] = (f16)aw[p].y;
                hv[2] = (f16)aw[p].z; hv[3] = (f16)aw[p].w;
                *(f16x4*)&As[srow + 32 * p][skc] = hv;
            }
        } else {
            #pragma unroll
            for (int p = 0; p < 2; p++)
                *(f16x8*)&As[hrow + 64 * p][hkc] = ah[p];
        }
        #pragma unroll
        for (int p = 0; p < 4; p++) {
            f16x4 hv;
            hv[0] = (f16)ww[p].x; hv[1] = (f16)ww[p].y;
            hv[2] = (f16)ww[p].z; hv[3] = (f16)ww[p].w;
            *(f16x4*)&Bs[srow + 32 * p][skc] = hv;
        }
        __syncthreads();

        f16x8 af[4], bf[4];
        #pragma unroll
        for (int mb = 0; mb < 4; mb++) af[mb] = *(const f16x8*)&As[wm + mb * 16 + lr][lg * 8];
        #pragma unroll
        for (int nb = 0; nb < 4; nb++) bf[nb] = *(const f16x8*)&Bs[wn + nb * 16 + lr][lg * 8];
        #pragma unroll
        for (int mb = 0; mb < 4; mb++)
            #pragma unroll
            for (int nb = 0; nb < 4; nb++)
                acc[mb][nb] = MFMA16(af[mb], bf[nb], acc[mb][nb]);
    }

    if (MODE == 2) {
        float* out = (float*)outp;
        #pragma unroll
        for (int nb = 0; nb < 4; nb++) {
            const int col = n0 + wn + nb * 16 + lr;
            const float bv = bias[col];
            #pragma unroll
            for (int mb = 0; mb < 4; mb++)
                #pragma unroll
                for (int r = 0; r < 4; r++) {
                    const int t = m0 + wm + mb * 16 + lg * 4 + r;
                    out[(size_t)t * DMODEL + col] = acc[mb][nb][r] + bv;
                }
        }
    } else {
        f16* out = (f16*)outp;
        const int h = bx * 2 + (w & 1);   // wave's 64 cols = one head
        #pragma unroll
        for (int mb = 0; mb < 4; mb++)
            #pragma unroll
            for (int r = 0; r < 4; r++) {
                const int m = m0 + wm + mb * 16 + lg * 4 + r;
                const int b = m >> 11;
                const int tt = m & 2047;
                f16* op = out + ((size_t)(b * NHEAD + h) * TSEQ + tt) * HDIM;
                if (MODE == 1) {
                    #pragma unroll
                    for (int pp = 0; pp < 2; pp++) {
                        const int d = pp * 16 + lr;          // 0..31
                        const float sn = sint[tt * 32 + d];
                        const float cs = cost[tt * 32 + d];
                        const float a  = acc[mb][pp][r];      // col d
                        const float bq = acc[mb][pp + 2][r];  // col d+32
                        op[d]      = (f16)((a * cs - bq * sn) * post_scale);
                        op[d + 32] = (f16)((bq * cs + a * sn) * post_scale);
                    }
                } else {
                    #pragma unroll
                    for (int nb = 0; nb < 4; nb++)
                        op[nb * 16 + lr] = (f16)acc[mb][nb][r];
                }
            }
    }
}

// Flash attention, fp16 MFMA. Block = 256 thr = 4 waves; Q-tile 64 rows
// (wave w owns rows w*16..+16, Q in registers), K-tile 64.
__global__ __launch_bounds__(256)
void flash16(const f16* __restrict__ Qh, const f16* __restrict__ Kh,
             const f16* __restrict__ Vh, f16* __restrict__ Ctx)
{
    __shared__ __align__(16) f16 Ks[64][72];      // row-major K-tile, 144B rows
    __shared__ __align__(16) f16 Vt[64][72];      // transposed V-tile: Vt[d][kk]
    __shared__ __align__(16) f16 Pl[4][16][72];   // per-wave P tile

    const int tid = threadIdx.x;
    const int w = tid >> 6;
    const int lane = tid & 63;
    const int lr = lane & 15;
    const int lg = lane >> 4;
    const int qt = blockIdx.x;      // 0..31
    const int bh = blockIdx.y;      // b*16+h

    // Q fragments (A-operand), 2 K-steps over D=64
    const f16* qbase = Qh + ((size_t)bh * TSEQ + qt * 64 + w * 16 + lr) * HDIM;
    f16x8 qf[2];
    #pragma unroll
    for (int ks = 0; ks < 2; ks++)
        qf[ks] = *(const f16x8*)(qbase + ks * 32 + lg * 8);

    f32x4 o_acc[4];
    float m_i[4], l_i[4];
    #pragma unroll
    for (int i = 0; i < 4; i++) {
        o_acc[i] = (f32x4)0.0f;
        m_i[i] = -1e30f;
        l_i[i] = 0.f;
    }

    const int srow = tid >> 3;         // 0..31 (+32)
    const int sd0  = (tid & 7) * 8;

    for (int kt = 0; kt < TSEQ / 64; ++kt) {
        // prefetch K/V into regs (global), then publish to LDS
        f16x8 kv[2], vv[2];
        #pragma unroll
        for (int p = 0; p < 2; p++) {
            const size_t g = ((size_t)bh * TSEQ + kt * 64 + srow + 32 * p) * HDIM + sd0;
            kv[p] = *(const f16x8*)(Kh + g);
            vv[p] = *(const f16x8*)(Vh + g);
        }
        __syncthreads();   // prior tile's Ks/Vt reads complete
        #pragma unroll
        for (int p = 0; p < 2; p++) {
            *(f16x8*)&Ks[srow + 32 * p][sd0] = kv[p];
            #pragma unroll
            for (int c = 0; c < 8; c++)
                Vt[sd0 + c][srow + 32 * p] = vv[p][c];
        }
        __syncthreads();

        // S = Q K^T : rows=q (A), cols=k (B from K rows)
        f32x4 s_acc[4];
        #pragma unroll
        for (int nb = 0; nb < 4; nb++) s_acc[nb] = (f32x4)0.0f;
        #pragma unroll
        for (int ks = 0; ks < 2; ks++) {
            #pragma unroll
            for (int nb = 0; nb < 4; nb++) {
                const f16x8 kf = *(const f16x8*)&Ks[nb * 16 + lr][ks * 32 + lg * 8];
                s_acc[nb] = MFMA16(qf[ks], kf, s_acc[nb]);
            }
        }

        // online softmax per row (row = lg*4+r, 64 cols = 4 nb x 16 lanes)
        #pragma unroll
        for (int r = 0; r < 4; r++) {
            float mx = fmaxf(fmaxf(s_acc[0][r], s_acc[1][r]),
                             fmaxf(s_acc[2][r], s_acc[3][r]));
            mx = fmaxf(mx, __shfl_xor(mx, 1));
            mx = fmaxf(mx, __shfl_xor(mx, 2));
            mx = fmaxf(mx, __shfl_xor(mx, 4));
            mx = fmaxf(mx, __shfl_xor(mx, 8));
            const float mn = fmaxf(m_i[r], mx);
            const float corr = __expf(m_i[r] - mn);
            m_i[r] = mn;
            float sum = 0.f;
            #pragma unroll
            for (int nb = 0; nb < 4; nb++) {
                const float p = __expf(s_acc[nb][r] - mn);
                s_acc[nb][r] = p;
                sum += p;
            }
            sum += __shfl_xor(sum, 1);
            sum += __shfl_xor(sum, 2);
            sum += __shfl_xor(sum, 4);
            sum += __shfl_xor(sum, 8);
            l_i[r] = l_i[r] * corr + sum;
            #pragma unroll
            for (int nb = 0; nb < 4; nb++) o_acc[nb][r] *= corr;
            // publish P row fp16 (per-wave region; wave-coherent, no barrier)
            #pragma unroll
            for (int nb = 0; nb < 4; nb++)
                Pl[w][lg * 4 + r][nb * 16 + lr] = (f16)s_acc[nb][r];
        }

        // O += P V  (A from Pl rows, B from Vt rows = V columns)
        #pragma unroll
        for (int ks = 0; ks < 2; ks++) {
            const f16x8 pf = *(const f16x8*)&Pl[w][lr][ks * 32 + lg * 8];
            #pragma unroll
            for (int nb = 0; nb < 4; nb++) {
                const f16x8 vf = *(const f16x8*)&Vt[nb * 16 + lr][ks * 32 + lg * 8];
                o_acc[nb] = MFMA16(pf, vf, o_acc[nb]);
            }
        }
    }

    const int b = bh >> 4, h = bh & 15;
    #pragma unroll
    for (int r = 0; r < 4; r++) {
        const float inv = 1.0f / l_i[r];
        const int t = qt * 64 + w * 16 + lg * 4 + r;
        f16* cp = Ctx + ((size_t)b * TSEQ + t) * DMODEL + h * HDIM;
        #pragma unroll
        for (int nb = 0; nb < 4; nb++)
            cp[nb * 16 + lr] = (f16)(o_acc[nb][r] * inv);
    }
}

extern "C" void kernel_launch(void* const* d_in, const int* in_sizes, int n_in,
                              void* d_out, int out_size, void* d_ws, size_t ws_size,
                              hipStream_t stream)
{
    const float* x  = (const float*)d_in[0];
    const float* Wq = (const float*)d_in[1];
    const float* Wk = (const float*)d_in[2];
    const float* Wv = (const float*)d_in[3];
    const float* Wo = (const float*)d_in[4];
    const float* bo = (const float*)d_in[5];
    float* out = (float*)d_out;

    const size_t NELT = (size_t)BATCH * TSEQ * DMODEL;   // 8388608
    const size_t WS_REQ = 4 * NELT * sizeof(f16) + 2 * (size_t)TSEQ * 32 * sizeof(float);
    if (ws_size < WS_REQ) return;   // clean failure instead of OOB crash

    f16* qh   = (f16*)d_ws;
    f16* kh   = qh + NELT;
    f16* vh   = kh + NELT;
    f16* ctxh = vh + NELT;
    float* sint = (float*)(ctxh + NELT);
    float* cost = sint + (size_t)TSEQ * 32;

    rope_table_kernel<<<256, 256, 0, stream>>>(sint, cost);

    dim3 pg(DMODEL / 128, (BATCH * TSEQ) / 128);   // (8, 64)
    mm16<1><<<pg, 256, 0, stream>>>(x, Wq, nullptr, qh, sint, cost, 0.125f);
    mm16<1><<<pg, 256, 0, stream>>>(x, Wk, nullptr, kh, sint, cost, 1.0f);
    mm16<0><<<pg, 256, 0, stream>>>(x, Wv, nullptr, vh, sint, cost, 1.0f);

    flash16<<<dim3(TSEQ / 64, BATCH * NHEAD), 256, 0, stream>>>(qh, kh, vh, ctxh);

    mm16<2><<<pg, 256, 0, stream>>>(ctxh, Wo, bo, out, nullptr, nullptr, 1.0f);
}

// Round 15
// 491.943 us; speedup vs baseline: 4.4404x; 1.1562x over previous
//
#include <hip/hip_runtime.h>
#include <math.h>

// RoPE attention forward — fp16 MFMA pipeline (round 14 resubmit of the
// Vt XOR-octet swizzle; rounds 11-13 never executed due to infra).
// Round-10 measured: total 568.8us; flash16 340us with SQ_LDS_BANK_CONFLICT
// 7.76e7 (~37% of flash cycles) — root cause: Vt transpose-write row stride
// 72hw => d-stride 8 rows == 0 mod 32 banks => ~16-way conflicts.
// Fix: involution swizzle Vt[d][kk ^ ((d>>3)<<3)] on write AND read.
// Desk-verified: write spreads 2 lanes/bank (free, m136); read stays at the
// uniform b128 floor; 16B alignment preserved (octet-aligned XOR).
// Everything else byte-identical to round 10.

typedef _Float16 f16;
typedef _Float16 f16x8 __attribute__((ext_vector_type(8)));
typedef _Float16 f16x4 __attribute__((ext_vector_type(4)));
typedef float f32x4 __attribute__((ext_vector_type(4)));

#define TSEQ 2048
#define DMODEL 1024
#define NHEAD 16
#define HDIM 64
#define BATCH 4

#define MFMA16(a, b, c) __builtin_amdgcn_mfma_f32_16x16x32_f16((a), (b), (c), 0, 0, 0)

__global__ __launch_bounds__(256)
void rope_table_kernel(float* __restrict__ sint, float* __restrict__ cost)
{
    int idx = blockIdx.x * 256 + threadIdx.x;   // [0, TSEQ*32)
    if (idx >= TSEQ * 32) return;
    int t = idx >> 5;
    int i = idx & 31;
    float inv32 = (float)pow(10000.0, -(double)i / 32.0);
    float ang = (float)t * inv32;
    sint[idx] = (float)sin((double)ang);
    cost[idx] = (float)cos((double)ang);
}

// MODE 0: A=x fp32, out fp16 head layout (V)
// MODE 1: A=x fp32, out fp16 head layout + RoPE * post_scale (Q,K)
// MODE 2: A=ctx fp16, out fp32 flat + bias (final projection)
// Tile 128x128, BK=32, 4 waves (2 M x 2 N), per-wave 64x64 = 4x4 MFMA frags.
template<int MODE>
__global__ __launch_bounds__(256)
void mm16(const void* __restrict__ Ap_, const float* __restrict__ W,
          const float* __restrict__ bias, void* __restrict__ outp,
          const float* __restrict__ sint, const float* __restrict__ cost,
          float post_scale)
{
    __shared__ __align__(16) f16 As[128][40];   // 40 = 32 + 8 pad; 80B rows
    __shared__ __align__(16) f16 Bs[128][40];

    const int tid = threadIdx.x;
    const int bx = blockIdx.x;    // N tile (0..7)
    const int by = blockIdx.y;    // M tile (0..63)
    const int w = tid >> 6;
    const int lane = tid & 63;
    const int lr = lane & 15;
    const int lg = lane >> 4;     // 0..3
    const int wm = (w >> 1) * 64;
    const int wn = (w & 1) * 64;
    const int m0 = by * 128, n0 = bx * 128;

    f32x4 acc[4][4];
    #pragma unroll
    for (int i = 0; i < 4; i++)
        #pragma unroll
        for (int j = 0; j < 4; j++) acc[i][j] = (f32x4)0.0f;

    // staging index maps
    const int srow = tid >> 3;            // fp32 path: 0..31 (+32p)
    const int skc  = (tid & 7) * 4;       // fp32: 4-float chunks
    const int hrow = tid >> 2;            // fp16 path rows 0..63 (+64p)
    const int hkc  = (tid & 3) * 8;       // fp16: 8-half chunks

    for (int k0 = 0; k0 < DMODEL; k0 += 32) {
        float4 ww[4];
        float4 aw[4];
        f16x8 ah[2];
        if (MODE < 2) {
            const float* A = (const float*)Ap_;
            #pragma unroll
            for (int p = 0; p < 4; p++)
                aw[p] = *(const float4*)(A + (size_t)(m0 + srow + 32 * p) * DMODEL + k0 + skc);
        } else {
            const f16* A = (const f16*)Ap_;
            #pragma unroll
            for (int p = 0; p < 2; p++)
                ah[p] = *(const f16x8*)(A + (size_t)(m0 + hrow + 64 * p) * DMODEL + k0 + hkc);
        }
        #pragma unroll
        for (int p = 0; p < 4; p++)
            ww[p] = *(const float4*)(W + (size_t)(n0 + srow + 32 * p) * DMODEL + k0 + skc);

        __syncthreads();   // previous iteration's frag reads done

        if (MODE < 2) {
            #pragma unroll
            for (int p = 0; p < 4; p++) {
                f16x4 hv;
                hv[0] = (f16)aw[p].x; hv[1] = (f16)aw[p].y;
                hv[2] = (f16)aw[p].z; hv[3] = (f16)aw[p].w;
                *(f16x4*)&As[srow + 32 * p][skc] = hv;
            }
        } else {
            #pragma unroll
            for (int p = 0; p < 2; p++)
                *(f16x8*)&As[hrow + 64 * p][hkc] = ah[p];
        }
        #pragma unroll
        for (int p = 0; p < 4; p++) {
            f16x4 hv;
            hv[0] = (f16)ww[p].x; hv[1] = (f16)ww[p].y;
            hv[2] = (f16)ww[p].z; hv[3] = (f16)ww[p].w;
            *(f16x4*)&Bs[srow + 32 * p][skc] = hv;
        }
        __syncthreads();

        f16x8 af[4], bf[4];
        #pragma unroll
        for (int mb = 0; mb < 4; mb++) af[mb] = *(const f16x8*)&As[wm + mb * 16 + lr][lg * 8];
        #pragma unroll
        for (int nb = 0; nb < 4; nb++) bf[nb] = *(const f16x8*)&Bs[wn + nb * 16 + lr][lg * 8];
        #pragma unroll
        for (int mb = 0; mb < 4; mb++)
            #pragma unroll
            for (int nb = 0; nb < 4; nb++)
                acc[mb][nb] = MFMA16(af[mb], bf[nb], acc[mb][nb]);
    }

    if (MODE == 2) {
        float* out = (float*)outp;
        #pragma unroll
        for (int nb = 0; nb < 4; nb++) {
            const int col = n0 + wn + nb * 16 + lr;
            const float bv = bias[col];
            #pragma unroll
            for (int mb = 0; mb < 4; mb++)
                #pragma unroll
                for (int r = 0; r < 4; r++) {
                    const int t = m0 + wm + mb * 16 + lg * 4 + r;
                    out[(size_t)t * DMODEL + col] = acc[mb][nb][r] + bv;
                }
        }
    } else {
        f16* out = (f16*)outp;
        const int h = bx * 2 + (w & 1);   // wave's 64 cols = one head
        #pragma unroll
        for (int mb = 0; mb < 4; mb++)
            #pragma unroll
            for (int r = 0; r < 4; r++) {
                const int m = m0 + wm + mb * 16 + lg * 4 + r;
                const int b = m >> 11;
                const int tt = m & 2047;
                f16* op = out + ((size_t)(b * NHEAD + h) * TSEQ + tt) * HDIM;
                if (MODE == 1) {
                    #pragma unroll
                    for (int pp = 0; pp < 2; pp++) {
                        const int d = pp * 16 + lr;          // 0..31
                        const float sn = sint[tt * 32 + d];
                        const float cs = cost[tt * 32 + d];
                        const float a  = acc[mb][pp][r];      // col d
                        const float bq = acc[mb][pp + 2][r];  // col d+32
                        op[d]      = (f16)((a * cs - bq * sn) * post_scale);
                        op[d + 32] = (f16)((bq * cs + a * sn) * post_scale);
                    }
                } else {
                    #pragma unroll
                    for (int nb = 0; nb < 4; nb++)
                        op[nb * 16 + lr] = (f16)acc[mb][nb][r];
                }
            }
    }
}

// Flash attention, fp16 MFMA. Block = 256 thr = 4 waves; Q-tile 64 rows
// (wave w owns rows w*16..+16, Q in registers), K-tile 64.
// Vt uses an octet XOR swizzle: element V[kk][d] lives at Vt[d][kk ^ VSWZ(d)]
// where VSWZ(d) = ((d>>3)&7)<<3 — involution per row; makes the transpose
// scatter-write conflict-free while keeping b128 reads octet-aligned.
__global__ __launch_bounds__(256)
void flash16(const f16* __restrict__ Qh, const f16* __restrict__ Kh,
             const f16* __restrict__ Vh, f16* __restrict__ Ctx)
{
    __shared__ __align__(16) f16 Ks[64][72];      // row-major K-tile, 144B rows
    __shared__ __align__(16) f16 Vt[64][72];      // swizzled transposed V-tile
    __shared__ __align__(16) f16 Pl[4][16][72];   // per-wave P tile

    const int tid = threadIdx.x;
    const int w = tid >> 6;
    const int lane = tid & 63;
    const int lr = lane & 15;
    const int lg = lane >> 4;
    const int qt = blockIdx.x;      // 0..31
    const int bh = blockIdx.y;      // b*16+h

    // Q fragments (A-operand), 2 K-steps over D=64
    const f16* qbase = Qh + ((size_t)bh * TSEQ + qt * 64 + w * 16 + lr) * HDIM;
    f16x8 qf[2];
    #pragma unroll
    for (int ks = 0; ks < 2; ks++)
        qf[ks] = *(const f16x8*)(qbase + ks * 32 + lg * 8);

    f32x4 o_acc[4];
    float m_i[4], l_i[4];
    #pragma unroll
    for (int i = 0; i < 4; i++) {
        o_acc[i] = (f32x4)0.0f;
        m_i[i] = -1e30f;
        l_i[i] = 0.f;
    }

    const int srow = tid >> 3;         // 0..31 (+32)
    const int sd0  = (tid & 7) * 8;    // note: VSWZ(sd0+c) == sd0 for c<8

    for (int kt = 0; kt < TSEQ / 64; ++kt) {
        // prefetch K/V into regs (global), then publish to LDS
        f16x8 kv[2], vv[2];
        #pragma unroll
        for (int p = 0; p < 2; p++) {
            const size_t g = ((size_t)bh * TSEQ + kt * 64 + srow + 32 * p) * HDIM + sd0;
            kv[p] = *(const f16x8*)(Kh + g);
            vv[p] = *(const f16x8*)(Vh + g);
        }
        __syncthreads();   // prior tile's Ks/Vt reads complete
        #pragma unroll
        for (int p = 0; p < 2; p++) {
            *(f16x8*)&Ks[srow + 32 * p][sd0] = kv[p];
            const int kks = (srow + 32 * p) ^ sd0;   // swizzled column
            #pragma unroll
            for (int c = 0; c < 8; c++)
                Vt[sd0 + c][kks] = vv[p][c];
        }
        __syncthreads();

        // S = Q K^T : rows=q (A), cols=k (B from K rows)
        f32x4 s_acc[4];
        #pragma unroll
        for (int nb = 0; nb < 4; nb++) s_acc[nb] = (f32x4)0.0f;
        #pragma unroll
        for (int ks = 0; ks < 2; ks++) {
            #pragma unroll
            for (int nb = 0; nb < 4; nb++) {
                const f16x8 kf = *(const f16x8*)&Ks[nb * 16 + lr][ks * 32 + lg * 8];
                s_acc[nb] = MFMA16(qf[ks], kf, s_acc[nb]);
            }
        }

        // online softmax per row (row = lg*4+r, 64 cols = 4 nb x 16 lanes)
        #pragma unroll
        for (int r = 0; r < 4; r++) {
            float mx = fmaxf(fmaxf(s_acc[0][r], s_acc[1][r]),
                             fmaxf(s_acc[2][r], s_acc[3][r]));
            mx = fmaxf(mx, __shfl_xor(mx, 1));
            mx = fmaxf(mx, __shfl_xor(mx, 2));
            mx = fmaxf(mx, __shfl_xor(mx, 4));
            mx = fmaxf(mx, __shfl_xor(mx, 8));
            const float mn = fmaxf(m_i[r], mx);
            const float corr = __expf(m_i[r] - mn);
            m_i[r] = mn;
            float sum = 0.f;
            #pragma unroll
            for (int nb = 0; nb < 4; nb++) {
                const float p = __expf(s_acc[nb][r] - mn);
                s_acc[nb][r] = p;
                sum += p;
            }
            sum += __shfl_xor(sum, 1);
            sum += __shfl_xor(sum, 2);
            sum += __shfl_xor(sum, 4);
            sum += __shfl_xor(sum, 8);
            l_i[r] = l_i[r] * corr + sum;
            #pragma unroll
            for (int nb = 0; nb < 4; nb++) o_acc[nb][r] *= corr;
            // publish P row fp16 (per-wave region; wave-coherent, no barrier)
            #pragma unroll
            for (int nb = 0; nb < 4; nb++)
                Pl[w][lg * 4 + r][nb * 16 + lr] = (f16)s_acc[nb][r];
        }

        // O += P V  (A from Pl rows, B from swizzled Vt rows = V columns)
        #pragma unroll
        for (int ks = 0; ks < 2; ks++) {
            const f16x8 pf = *(const f16x8*)&Pl[w][lr][ks * 32 + lg * 8];
            #pragma unroll
            for (int nb = 0; nb < 4; nb++) {
                const int dv = nb * 16 + lr;
                const int kc = (ks * 32 + lg * 8) ^ (((dv >> 3) & 7) << 3);
                const f16x8 vf = *(const f16x8*)&Vt[dv][kc];
                o_acc[nb] = MFMA16(pf, vf, o_acc[nb]);
            }
        }
    }

    const int b = bh >> 4, h = bh & 15;
    #pragma unroll
    for (int r = 0; r < 4; r++) {
        const float inv = 1.0f / l_i[r];
        const int t = qt * 64 + w * 16 + lg * 4 + r;
        f16* cp = Ctx + ((size_t)b * TSEQ + t) * DMODEL + h * HDIM;
        #pragma unroll
        for (int nb = 0; nb < 4; nb++)
            cp[nb * 16 + lr] = (f16)(o_acc[nb][r] * inv);
    }
}

extern "C" void kernel_launch(void* const* d_in, const int* in_sizes, int n_in,
                              void* d_out, int out_size, void* d_ws, size_t ws_size,
                              hipStream_t stream)
{
    const float* x  = (const float*)d_in[0];
    const float* Wq = (const float*)d_in[1];
    const float* Wk = (const float*)d_in[2];
    const float* Wv = (const float*)d_in[3];
    const float* Wo = (const float*)d_in[4];
    const float* bo = (const float*)d_in[5];
    float* out = (float*)d_out;

    const size_t NELT = (size_t)BATCH * TSEQ * DMODEL;   // 8388608
    const size_t WS_REQ = 4 * NELT * sizeof(f16) + 2 * (size_t)TSEQ * 32 * sizeof(float);
    if (ws_size < WS_REQ) return;   // clean failure instead of OOB crash

    f16* qh   = (f16*)d_ws;
    f16* kh   = qh + NELT;
    f16* vh   = kh + NELT;
    f16* ctxh = vh + NELT;
    float* sint = (float*)(ctxh + NELT);
    float* cost = sint + (size_t)TSEQ * 32;

    rope_table_kernel<<<256, 256, 0, stream>>>(sint, cost);

    dim3 pg(DMODEL / 128, (BATCH * TSEQ) / 128);   // (8, 64)
    mm16<1><<<pg, 256, 0, stream>>>(x, Wq, nullptr, qh, sint, cost, 0.125f);
    mm16<1><<<pg, 256, 0, stream>>>(x, Wk, nullptr, kh, sint, cost, 1.0f);
    mm16<0><<<pg, 256, 0, stream>>>(x, Wv, nullptr, vh, sint, cost, 1.0f);

    flash16<<<dim3(TSEQ / 64, BATCH * NHEAD), 256, 0, stream>>>(qh, kh, vh, ctxh);

    mm16<2><<<pg, 256, 0, stream>>>(ctxh, Wo, bo, out, nullptr, nullptr, 1.0f);
}